// Round 1
// baseline (382.838 us; speedup 1.0000x reference)
//
#include <hip/hip_runtime.h>
#include <math.h>

#define C_DIM 256

// ---------------------------------------------------------------------------
// CAM: aTa = A^T A per batch (A = x reshaped [L, C]); S = softmax(aTa, axis=-1);
// out = gamma * (A @ S) + x.
// gamma is a learnable scalar initialized to 0 => out == x exactly when gamma==0.
//
// Structure (graph-capture safe, identical work per call for identical inputs):
//   1. copy_kernel    [device-gated on gamma==0]  out = x via float4 shader
//      copy at HBM roofline. NOTE: this replaces the previous hipMemcpyAsync —
//      a captured D2D memcpy node lowers to a non-shader blit (~0.62 TB/s
//      copied-bytes => ~365 us for 226.5 MB); the shader copy does the same
//      432 MiB of HBM traffic at ~6.5 TB/s => ~70 us.
//   2. gram_kernel    [device-gated on gamma!=0]  aTa = A^T A
//   3. softmax_kernel [device-gated]              row softmax in-place
//   4. apply_kernel   [device-gated]              out = gamma*(A@S) + x
//      (writes EVERY output element itself, so the gamma!=0 path does not
//      depend on copy_kernel having run)
// ---------------------------------------------------------------------------

// Pure streaming copy, hot path (gamma==0). grid = 2048 x 256 => 524,288 lanes;
// 14,155,776 float4s / 524,288 = exactly 27 iters/thread. 16 B/lane coalesced.
__global__ __launch_bounds__(256) void copy_kernel(const float* __restrict__ x,
                                                   const float* __restrict__ gamma,
                                                   float* __restrict__ out,
                                                   long n) {
    if (gamma[0] != 0.0f) return;   // apply_kernel produces out on this path

    long n4 = n >> 2;
    const float4* __restrict__ src = (const float4*)x;
    float4* __restrict__ dst = (float4*)out;
    long stride = (long)gridDim.x * blockDim.x;
    for (long i = (long)blockIdx.x * blockDim.x + threadIdx.x; i < n4; i += stride)
        dst[i] = src[i];

    // scalar tail (n % 4 == 0 for this problem, but stay general)
    long tail = n & 3;
    if (blockIdx.x == 0 && (long)threadIdx.x < tail) {
        long base = n4 << 2;
        out[base + threadIdx.x] = x[base + threadIdx.x];
    }
}

// Gram matrix, cold path only. grid.x = B * 16 (16 tiles of 64x64 covering
// 256x256); block = 256 threads = 16x16, each owns a 4x4 micro-tile.
__global__ void gram_kernel(const float* __restrict__ x,
                            const float* __restrict__ gamma,
                            float* __restrict__ aTa,
                            int B, long L) {
    if (gamma[0] == 0.0f) return;   // zero-gate: pipeline contributes nothing

    int bid  = blockIdx.x;
    int tile = bid % 16;
    int b    = bid / 16;
    int ti   = tile % 4;            // 64-col strip for i
    int tj   = tile / 4;            // 64-col strip for j

    int tid = threadIdx.x;
    int tx  = tid % 16;
    int ty  = tid / 16;
    int ci  = ti * 64 + tx * 4;     // 4 consecutive i-columns
    int cj  = tj * 64 + ty * 4;     // 4 consecutive j-columns

    float acc[4][4];
#pragma unroll
    for (int u = 0; u < 4; ++u)
#pragma unroll
        for (int v = 0; v < 4; ++v) acc[u][v] = 0.0f;

    const float* base = x + (long)b * L * C_DIM;
    for (long l = 0; l < L; ++l) {
        const float* row = base + l * C_DIM;
        float4 ai = *(const float4*)(row + ci);
        float4 aj = *(const float4*)(row + cj);
        float au[4] = {ai.x, ai.y, ai.z, ai.w};
        float av[4] = {aj.x, aj.y, aj.z, aj.w};
#pragma unroll
        for (int u = 0; u < 4; ++u)
#pragma unroll
            for (int v = 0; v < 4; ++v) acc[u][v] += au[u] * av[v];
    }

    float* dst = aTa + (long)b * C_DIM * C_DIM;
#pragma unroll
    for (int u = 0; u < 4; ++u) {
        float4 r = {acc[u][0], acc[u][1], acc[u][2], acc[u][3]};
        *(float4*)(dst + (long)(ci + u) * C_DIM + cj) = r;
    }
}

// Row softmax over last axis of aTa in-place. grid.x = B*C ; block = 256 (==C)
__global__ void softmax_kernel(const float* __restrict__ gamma,
                               float* __restrict__ aTa) {
    if (gamma[0] == 0.0f) return;

    float* p = aTa + (long)blockIdx.x * C_DIM;
    int j    = threadIdx.x;
    int lane = j & 63, wave = j >> 6;
    __shared__ float sred[4];

    float v = p[j];

    float m = v;
#pragma unroll
    for (int o = 32; o > 0; o >>= 1) m = fmaxf(m, __shfl_down(m, o));
    if (lane == 0) sred[wave] = m;
    __syncthreads();
    if (j == 0) {
        float mm = sred[0];
        for (int w = 1; w < 4; ++w) mm = fmaxf(mm, sred[w]);
        sred[0] = mm;
    }
    __syncthreads();
    m = sred[0];
    __syncthreads();

    float e = expf(v - m);
    float s = e;
#pragma unroll
    for (int o = 32; o > 0; o >>= 1) s += __shfl_down(s, o);
    if (lane == 0) sred[wave] = s;
    __syncthreads();
    if (j == 0) {
        float t = 0.0f;
        for (int w = 0; w < 4; ++w) t += sred[w];
        sred[0] = t;
    }
    __syncthreads();

    p[j] = e / sred[0];
}

// Cold path only: out = gamma * (A @ S) + x. Writes every output element, so
// it does NOT depend on copy_kernel. block = 256 (==C); row-per-block GEMV.
__global__ void apply_kernel(const float* __restrict__ x,
                             const float* __restrict__ gamma,
                             const float* __restrict__ S,
                             float* __restrict__ out,
                             int B, long L) {
    float g = gamma[0];
    if (g == 0.0f) return;          // out produced by copy_kernel on this path

    __shared__ float arow[C_DIM];
    long totalRows = (long)B * L;
    int j = threadIdx.x;
    for (long r = blockIdx.x; r < totalRows; r += gridDim.x) {
        long b = r / L;
        const float* xr = x + r * C_DIM;
        __syncthreads();
        arow[j] = xr[j];
        __syncthreads();
        const float* Sb = S + b * C_DIM * C_DIM;
        float sum = 0.0f;
        for (int c = 0; c < C_DIM; ++c)
            sum += arow[c] * Sb[(long)c * C_DIM + j];
        out[r * C_DIM + j] = g * sum + arow[j];
    }
}

extern "C" void kernel_launch(void* const* d_in, const int* in_sizes, int n_in,
                              void* d_out, int out_size, void* d_ws, size_t ws_size,
                              hipStream_t stream) {
    const float* x     = (const float*)d_in[0];
    const float* gamma = (const float*)d_in[1];
    float*       out   = (float*)d_out;

    const int  B = 2;
    long n = (long)in_sizes[0];            // B*H*W*D*C
    long L = n / ((long)B * C_DIM);        // 110592

    float* aTa = (float*)d_ws;             // B*C*C fp32 = 512 KB scratch

    copy_kernel   <<<dim3(2048),     dim3(256), 0, stream>>>(x, gamma, out, n);
    gram_kernel   <<<dim3(B * 16),   dim3(256), 0, stream>>>(x, gamma, aTa, B, L);
    softmax_kernel<<<dim3(B * C_DIM), dim3(256), 0, stream>>>(gamma, aTa);
    apply_kernel  <<<dim3(8192),     dim3(256), 0, stream>>>(x, gamma, aTa, out, B, L);
}